// Round 1
// baseline (1418.877 us; speedup 1.0000x reference)
//
#include <hip/hip_runtime.h>

// TwoBranchDH_SFNN: B=128, T=2048, H=512, D_IN=40, D_OUT=1
//
// Kernel 1 (sfnn_scan_kernel): one thread per (b,h) chain.
//   - W1[h,:], W2[h,:] in 40 VGPRs; alpha/beta precomputed per thread.
//   - x[b,t,:] is block-uniform -> scalar loads; distance-2 register prefetch.
//   - mem*Wo[h] written to LDS [TT][HB+1]; batched transpose-reduce every TT=32
//     steps (avoids a 6-deep shuffle-reduce latency chain per timestep).
//   - HSPLIT=2 over H -> 256 blocks (1/CU), partials to d_ws.
// Kernel 2 (sfnn_out_kernel): sum HSPLIT partials + bo, sigmoid, float4 stores.

#define NB 128
#define NT 2048
#define NH 512
#define DIN 40
#define HSPLIT 2
#define HB (NH / HSPLIT)   // 256 threads/block = 4 waves
#define TT 32
#define LSTR (HB + 1)      // +1 pad: conflict-free strided reads in reduce

__global__ __launch_bounds__(HB, 1) void sfnn_scan_kernel(
    const float* __restrict__ x,
    const float* __restrict__ W1, const float* __restrict__ b1v,
    const float* __restrict__ W2, const float* __restrict__ b2v,
    const float* __restrict__ Wo,
    const float* __restrict__ tau_m, const float* __restrict__ tau_n1,
    const float* __restrict__ tau_n2,
    float* __restrict__ partial)   // [HSPLIT][NB][NT]
{
    const int blk = blockIdx.x;
    const int b   = blk >> 1;      // / HSPLIT
    const int hs  = blk & 1;       // % HSPLIT
    const int tid = threadIdx.x;
    const int h   = hs * HB + tid;

    // Per-thread weights and gates (registers)
    float w1r[20], w2r[20];
#pragma unroll
    for (int k = 0; k < 20; ++k) {
        w1r[k] = W1[h * 20 + k];
        w2r[k] = W2[h * 20 + k];
    }
    const float bb1   = b1v[h];
    const float bb2   = b2v[h];
    const float alpha = 1.f / (1.f + __expf(-tau_m[h]));
    const float beta1 = 1.f / (1.f + __expf(-tau_n1[h]));
    const float beta2 = 1.f / (1.f + __expf(-tau_n2[h]));
    const float wo    = Wo[h];
    const float ia  = 1.f - alpha;
    const float ib1 = 1.f - beta1;
    const float ib2 = 1.f - beta2;

    __shared__ float pbuf[TT * LSTR];

    const float* __restrict__ xb = x + (size_t)b * NT * DIN;
    float d1 = 0.f, d2 = 0.f, mem = 0.f;

    // Distance-2 prefetch ping-pong buffers (block-uniform -> scalar loads)
    float xc[DIN], xn[DIN];
#pragma unroll
    for (int k = 0; k < DIN; ++k) xc[k] = xb[k];
#pragma unroll
    for (int k = 0; k < DIN; ++k) xn[k] = xb[DIN + k];

// Consume BUF at timestep T_, then refill BUF with x[T_+2] (clamped).
#define STEP2(BUF, T_)                                                        \
    {                                                                         \
        float i1 = bb1, i2 = bb2;                                             \
        _Pragma("unroll")                                                     \
        for (int k = 0; k < 20; ++k) {                                        \
            i1 = fmaf(BUF[k],      w1r[k], i1);                               \
            i2 = fmaf(BUF[20 + k], w2r[k], i2);                               \
        }                                                                     \
        const int tn_ = ((T_) + 2 < NT) ? ((T_) + 2) : (NT - 1);              \
        const float* __restrict__ xp_ = xb + (size_t)tn_ * DIN;               \
        _Pragma("unroll")                                                     \
        for (int k = 0; k < DIN; ++k) BUF[k] = xp_[k];                        \
        d1  = fmaf(beta1, d1, ib1 * i1);                                      \
        d2  = fmaf(beta2, d2, ib2 * i2);                                      \
        mem = fmaf(alpha, mem, ia * (d1 + d2));                               \
        pbuf[((T_) - t0) * LSTR + tid] = mem * wo;                            \
    }

    for (int t0 = 0; t0 < NT; t0 += TT) {
#pragma unroll 2
        for (int tt = 0; tt < TT; tt += 2) {
            STEP2(xc, t0 + tt);
            STEP2(xn, t0 + tt + 1);
        }
        __syncthreads();
        // Batched reduce: 8 threads per timestep, 32 timesteps.
        {
            const int t = tid >> 3;   // 0..31
            const int j = tid & 7;    // 0..7
            const float* row = &pbuf[t * LSTR + j * 32];
            float s0 = 0.f, s1 = 0.f, s2 = 0.f, s3 = 0.f;
#pragma unroll
            for (int m = 0; m < 32; m += 4) {
                s0 += row[m + 0];
                s1 += row[m + 1];
                s2 += row[m + 2];
                s3 += row[m + 3];
            }
            float s = (s0 + s1) + (s2 + s3);
            s += __shfl_down(s, 4, 64);
            s += __shfl_down(s, 2, 64);
            s += __shfl_down(s, 1, 64);
            if (j == 0) partial[((size_t)hs * NB + b) * NT + t0 + t] = s;
        }
        __syncthreads();
    }
#undef STEP2
}

__global__ __launch_bounds__(256) void sfnn_out_kernel(
    const float* __restrict__ partial, const float* __restrict__ bo,
    float* __restrict__ out)
{
    const int i = blockIdx.x * 256 + threadIdx.x;   // float4 index
    const float bov = bo[0];
    const float4 a = ((const float4*)partial)[i];
    const float4 c = ((const float4*)(partial + (size_t)NB * NT))[i];
    float4 r;
    r.x = 1.f / (1.f + __expf(-(a.x + c.x + bov)));
    r.y = 1.f / (1.f + __expf(-(a.y + c.y + bov)));
    r.z = 1.f / (1.f + __expf(-(a.z + c.z + bov)));
    r.w = 1.f / (1.f + __expf(-(a.w + c.w + bov)));
    ((float4*)out)[i] = r;
}

extern "C" void kernel_launch(void* const* d_in, const int* in_sizes, int n_in,
                              void* d_out, int out_size, void* d_ws, size_t ws_size,
                              hipStream_t stream)
{
    const float* x      = (const float*)d_in[0];
    const float* W1     = (const float*)d_in[1];
    const float* b1     = (const float*)d_in[2];
    const float* W2     = (const float*)d_in[3];
    const float* b2     = (const float*)d_in[4];
    const float* Wo     = (const float*)d_in[5];
    const float* bo     = (const float*)d_in[6];
    const float* tau_m  = (const float*)d_in[7];
    const float* tau_n1 = (const float*)d_in[8];
    const float* tau_n2 = (const float*)d_in[9];

    float* partial = (float*)d_ws;       // HSPLIT * NB * NT floats = 2 MB
    float* out     = (float*)d_out;      // NB * NT floats

    hipLaunchKernelGGL(sfnn_scan_kernel, dim3(NB * HSPLIT), dim3(HB), 0, stream,
                       x, W1, b1, W2, b2, Wo, tau_m, tau_n1, tau_n2, partial);
    hipLaunchKernelGGL(sfnn_out_kernel, dim3((NB * NT) / (4 * 256)), dim3(256),
                       0, stream, partial, bo, out);
}

// Round 2
// 430.354 us; speedup vs baseline: 3.2970x; 3.2970x over previous
//
#include <hip/hip_runtime.h>

// TwoBranchDH_SFNN: B=128, T=2048, H=512, D_IN=40, D_OUT=1
//
// R2: eliminate SMEM (s_load) from the hot loop — R1 died on lgkmcnt(0)
// full-drain semantics for out-of-order SMEM (2070 cyc/step).
//   - x staged per 32-step chunk into LDS via coalesced float4 vector loads
//     (vmcnt path), double-buffered across chunks; one vmcnt wait per chunk.
//   - inner loop: broadcast ds_read_b128 into register ping-pong xr[2][10],
//     distance-1 prefetch; DS is in-order -> fine-grained lgkm waits.
//   - (1-beta) folded into weights/biases: 40 FMA + 5 state ops per step.
//   - conflict-free transpose-reduce every 32 steps (banks (t+m)&31 distinct,
//     2 lanes/bank = free), cross-wave via shfl_down(32) + 4x32 LDS.

#define NB 128
#define NT 2048
#define NH 512
#define DIN 40
#define HSPLIT 2
#define HB (NH / HSPLIT)     // 256 threads/block = 4 waves
#define TT 32
#define NCHUNK (NT / TT)     // 64
#define LSTR (HB + 1)        // 257: pad -> banks (t+m)&31 in reduce
#define XCHUNK_F4 (TT * DIN / 4)   // 320 float4 per chunk

__global__ __launch_bounds__(HB, 1) void sfnn_scan_kernel(
    const float* __restrict__ x,
    const float* __restrict__ W1, const float* __restrict__ b1v,
    const float* __restrict__ W2, const float* __restrict__ b2v,
    const float* __restrict__ Wo,
    const float* __restrict__ tau_m, const float* __restrict__ tau_n1,
    const float* __restrict__ tau_n2,
    float* __restrict__ partial)   // [HSPLIT][NB][NT]
{
    const int blk = blockIdx.x;
    const int b   = blk >> 1;
    const int hs  = blk & 1;
    const int tid = threadIdx.x;
    const int h   = hs * HB + tid;

    __shared__ float xsf[2 * TT * DIN];    // 10240 B, double-buffered x stage
    __shared__ float pbuf[TT * LSTR];      // 32896 B
    __shared__ float wp[4 * TT];           // 512 B  (wave partials)

    // Gates
    const float alpha = 1.f / (1.f + __expf(-tau_m[h]));
    const float beta1 = 1.f / (1.f + __expf(-tau_n1[h]));
    const float beta2 = 1.f / (1.f + __expf(-tau_n2[h]));
    const float ia  = 1.f - alpha;
    const float ib1 = 1.f - beta1;
    const float ib2 = 1.f - beta2;
    const float wo  = Wo[h];
    const float bias1 = b1v[h] * ib1;
    const float bias2 = b2v[h] * ib2;

    // Weights with (1-beta) folded in
    float w1r[20], w2r[20];
#pragma unroll
    for (int k = 0; k < 20; ++k) {
        w1r[k] = W1[h * 20 + k] * ib1;
        w2r[k] = W2[h * 20 + k] * ib2;
    }

    const float* __restrict__ xb = x + (size_t)b * NT * DIN;

    // Stage chunk 0 into buffer 0
    {
        const float4* gs = (const float4*)xb;
        float4 a = gs[tid];
        ((float4*)xsf)[tid] = a;
        if (tid < XCHUNK_F4 - HB) {
            float4 c2 = gs[tid + HB];
            ((float4*)xsf)[tid + HB] = c2;
        }
    }
    __syncthreads();

    // Register ping-pong x buffers (distance-1 prefetch from LDS)
    float4 xr[2][10];
#pragma unroll
    for (int q = 0; q < 10; ++q) xr[0][q] = ((const float4*)xsf)[q];

    float d1 = 0.f, d2 = 0.f, mem = 0.f;

    for (int c = 0; c < NCHUNK; ++c) {
        const int cur = c & 1;
        float* xcur = xsf + cur * (TT * DIN);
        float* xnxt = xsf + (1 - cur) * (TT * DIN);

        // Issue global loads for chunk c+1 (clamped; vmcnt, waited at tt==15)
        const int cn = (c + 1 < NCHUNK) ? c + 1 : NCHUNK - 1;
        const float4* gs = (const float4*)(xb + (size_t)cn * TT * DIN);
        float4 g0 = gs[tid];
        float4 g1;
        if (tid < XCHUNK_F4 - HB) g1 = gs[tid + HB];

#pragma unroll
        for (int tt = 0; tt < TT; ++tt) {
            const int p = tt & 1;
            // Prefetch next step's x (broadcast ds_read_b128 x10)
            const float4* src = (tt < TT - 1)
                ? (const float4*)(xcur + (tt + 1) * DIN)
                : (const float4*)xnxt;   // chunk c+1, slot 0 (after barrier)
#pragma unroll
            for (int q = 0; q < 10; ++q) xr[1 - p][q] = src[q];

            // 40 FMAs on xr[p]; 4 accumulator chains for ILP
            const float* xv = (const float*)xr[p];
            float a0 = bias1, a1 = 0.f, b0 = bias2, b1a = 0.f;
#pragma unroll
            for (int k = 0; k < 10; ++k) {
                a0  = fmaf(xv[k],      w1r[k],      a0);
                a1  = fmaf(xv[10 + k], w1r[10 + k], a1);
                b0  = fmaf(xv[20 + k], w2r[k],      b0);
                b1a = fmaf(xv[30 + k], w2r[10 + k], b1a);
            }
            d1  = fmaf(beta1, d1, a0 + a1);
            d2  = fmaf(beta2, d2, b0 + b1a);
            mem = fmaf(alpha, mem, ia * (d1 + d2));
            pbuf[tt * LSTR + tid] = mem * wo;

            if (tt == 15) {
                // Commit staged chunk c+1 to LDS (vmcnt wait lands here)
                ((float4*)xnxt)[tid] = g0;
                if (tid < XCHUNK_F4 - HB) ((float4*)xnxt)[tid + HB] = g1;
            }
            if (tt == TT - 2) __syncthreads();  // xnxt visible before tt=31 prefetch
        }
        __syncthreads();   // pbuf complete

        // Transpose-reduce: 8 (t-groups of 32 h) x 32 t, conflict-free
        {
            const int t = tid & 31;
            const int j = tid >> 5;                  // 0..7
            const float* row = pbuf + t * LSTR + j * 32;
            float s0 = 0.f, s1 = 0.f, s2 = 0.f, s3 = 0.f;
#pragma unroll
            for (int m = 0; m < 32; m += 4) {
                s0 += row[m + 0];
                s1 += row[m + 1];
                s2 += row[m + 2];
                s3 += row[m + 3];
            }
            float s = (s0 + s1) + (s2 + s3);
            s += __shfl_down(s, 32, 64);             // j=2w + j=2w+1
            if ((tid & 63) < 32) wp[(tid >> 6) * TT + t] = s;
        }
        __syncthreads();
        if (tid < TT) {
            float r = wp[tid] + wp[TT + tid] + wp[2 * TT + tid] + wp[3 * TT + tid];
            partial[((size_t)hs * NB + b) * NT + c * TT + tid] = r;
        }
        // next chunk's pbuf writes are separated from this chunk's reads by
        // the barrier above; wp reuse separated by next chunk's barriers.
    }
}

__global__ __launch_bounds__(256) void sfnn_out_kernel(
    const float* __restrict__ partial, const float* __restrict__ bo,
    float* __restrict__ out)
{
    const int i = blockIdx.x * 256 + threadIdx.x;   // float4 index
    const float bov = bo[0];
    const float4 a = ((const float4*)partial)[i];
    const float4 c = ((const float4*)(partial + (size_t)NB * NT))[i];
    float4 r;
    r.x = 1.f / (1.f + __expf(-(a.x + c.x + bov)));
    r.y = 1.f / (1.f + __expf(-(a.y + c.y + bov)));
    r.z = 1.f / (1.f + __expf(-(a.z + c.z + bov)));
    r.w = 1.f / (1.f + __expf(-(a.w + c.w + bov)));
    ((float4*)out)[i] = r;
}

extern "C" void kernel_launch(void* const* d_in, const int* in_sizes, int n_in,
                              void* d_out, int out_size, void* d_ws, size_t ws_size,
                              hipStream_t stream)
{
    const float* x      = (const float*)d_in[0];
    const float* W1     = (const float*)d_in[1];
    const float* b1     = (const float*)d_in[2];
    const float* W2     = (const float*)d_in[3];
    const float* b2     = (const float*)d_in[4];
    const float* Wo     = (const float*)d_in[5];
    const float* bo     = (const float*)d_in[6];
    const float* tau_m  = (const float*)d_in[7];
    const float* tau_n1 = (const float*)d_in[8];
    const float* tau_n2 = (const float*)d_in[9];

    float* partial = (float*)d_ws;       // HSPLIT * NB * NT floats = 2 MB
    float* out     = (float*)d_out;      // NB * NT floats

    hipLaunchKernelGGL(sfnn_scan_kernel, dim3(NB * HSPLIT), dim3(HB), 0, stream,
                       x, W1, b1, W2, b2, Wo, tau_m, tau_n1, tau_n2, partial);
    hipLaunchKernelGGL(sfnn_out_kernel, dim3((NB * NT) / (4 * 256)), dim3(256),
                       0, stream, partial, bo, out);
}

// Round 3
// 240.127 us; speedup vs baseline: 5.9089x; 1.7922x over previous
//
#include <hip/hip_runtime.h>

// TwoBranchDH_SFNN: B=128, T=2048, H=512, D_IN=40, D_OUT=1
//
// R3: R2 was LDS-bandwidth-bound (broadcast ds_read still moves 16 B/lane:
// 21.5 GB LDS traffic floor ~300 µs). Replace the VALU projection with a
// fused bf16 MFMA GEMM per 32-step chunk; scan reads a bf16 D-tile.
//   block = (b, h-half): GEMM [32t x 64k] x [64k x 512n] -> D1|D2 tile,
//   bias as k=40 column of ones, (1-beta) folded into W/bias.
//   D-tile bf16 [n][32 t], XOR-swizzle on 4-t granules (conflict-free for
//   MFMA C-layout b64 writes AND scan b64 reads).
//   Scan: 6 VALU/step/thread, states in registers; pbuf reduce as R2.

#define NB 128
#define NT 2048
#define NH 512
#define TT 32
#define NCHUNK 64
#define WSTR 72           // Wimg/Aimg k-stride in halves (144 B, 16B-aligned)

typedef __attribute__((ext_vector_type(8))) short short8;
typedef __attribute__((ext_vector_type(4))) float f32x4;

__device__ __forceinline__ unsigned short f2bf(float f) {
    unsigned u = __float_as_uint(f);
    u += 0x7fff + ((u >> 16) & 1);          // round-to-nearest-even
    return (unsigned short)(u >> 16);
}
__device__ __forceinline__ float bf2f(unsigned short h) {
    return __uint_as_float(((unsigned)h) << 16);
}

// LDS carve (111744 B total):
//   region0 [0, 73728):      Wimg [512 n][72 k] bf16  -> reused as
//                            Dl   [512 n][32 t] bf16 (32768 B)
//   region1 [73728, 78336):  Aimg [32 m][72 k] bf16
//   region2 [78336, 111232): pbuf [32 t][257] f32
//   region3 [111232,111744): wp   [4][32] f32
#define SM_A    73728
#define SM_PB   78336
#define SM_WP   111232
#define SM_TOT  111744

__global__ __launch_bounds__(256, 1) void sfnn_scan_kernel(
    const float* __restrict__ x,
    const float* __restrict__ W1, const float* __restrict__ b1v,
    const float* __restrict__ W2, const float* __restrict__ b2v,
    const float* __restrict__ Wo,
    const float* __restrict__ tau_m, const float* __restrict__ tau_n1,
    const float* __restrict__ tau_n2,
    float* __restrict__ partial)   // [2][NB][NT]
{
    __shared__ __align__(16) unsigned char smem[SM_TOT];
    unsigned short* Wimg = (unsigned short*)smem;            // phase 0
    unsigned short* Dl   = (unsigned short*)smem;            // steady state
    unsigned short* Aimg = (unsigned short*)(smem + SM_A);
    float*          pbuf = (float*)(smem + SM_PB);
    float*          wp   = (float*)(smem + SM_WP);

    const int blk = blockIdx.x;
    const int b   = blk >> 1;
    const int hs  = blk & 1;
    const int tid = threadIdx.x;
    const int w   = tid >> 6;       // wave 0..3
    const int l   = tid & 63;
    const int n16 = l & 15;
    const int q   = l >> 4;         // 0..3

    const int h = hs * 256 + tid;

    // ---- gates (also scan constants) ----
    const float alpha = 1.f / (1.f + __expf(-tau_m[h]));
    const float beta1 = 1.f / (1.f + __expf(-tau_n1[h]));
    const float beta2 = 1.f / (1.f + __expf(-tau_n2[h]));
    const float ia  = 1.f - alpha;
    const float ib1 = 1.f - beta1;
    const float ib2 = 1.f - beta2;
    const float wo  = Wo[h];

    // ---- phase 0: build Wimg cols tid (D1) and tid+256 (D2), bf16 ----
    // col n<256:  k<20 -> W1[h][k]*ib1 ; k==40 -> b1[h]*ib1 ; else 0
    // col n>=256: 20<=k<40 -> W2[h][k-20]*ib2 ; k==40 -> b2[h]*ib2 ; else 0
    for (int k = 0; k < WSTR; ++k) {
        float v1 = 0.f, v2 = 0.f;
        if (k < 20)       v1 = W1[h * 20 + k] * ib1;
        else if (k == 40) v1 = b1v[h] * ib1;
        if (k >= 20 && k < 40) v2 = W2[h * 20 + (k - 20)] * ib2;
        else if (k == 40)      v2 = b2v[h] * ib2;
        Wimg[tid * WSTR + k]         = f2bf(v1);
        Wimg[(tid + 256) * WSTR + k] = f2bf(v2);
    }

    // A-image static part: rows m=0..31, k=40 -> 1.0, k=41..71 -> 0
    if (tid < 32) {
        Aimg[tid * WSTR + 40] = 0x3F80;   // bf16 1.0
        for (int k = 41; k < WSTR; ++k) Aimg[tid * WSTR + k] = 0;
    }

    // load chunk 0 x into regs (f4 idx: tid, and 256+tid for tid<64)
    const float* __restrict__ xb = x + (size_t)b * NT * 40;
    const float4* __restrict__ xf4 = (const float4*)xb;     // 320 f4/chunk
    float4 xr0 = xf4[tid];
    float4 xr1;
    if (tid < 64) xr1 = xf4[256 + tid];

    __syncthreads();

    // ---- B-fragments: wave w covers n in [w*128, w*128+128) ----
    short8 bfr[8][2];
#pragma unroll
    for (int nt = 0; nt < 8; ++nt)
#pragma unroll
        for (int kf = 0; kf < 2; ++kf)
            bfr[nt][kf] = *(const short8*)&Wimg[(w * 128 + nt * 16 + n16) * WSTR
                                                + kf * 32 + q * 8];

    // write A-image chunk 0 from regs; then prefetch chunk 1
    {
        const int m = tid / 10, k0 = (tid % 10) * 4;
        ushort4 a = { f2bf(xr0.x), f2bf(xr0.y), f2bf(xr0.z), f2bf(xr0.w) };
        *(ushort4*)&Aimg[m * WSTR + k0] = a;
        if (tid < 64) {
            const int i2 = 256 + tid, m2 = i2 / 10, k2 = (i2 % 10) * 4;
            ushort4 a2 = { f2bf(xr1.x), f2bf(xr1.y), f2bf(xr1.z), f2bf(xr1.w) };
            *(ushort4*)&Aimg[m2 * WSTR + k2] = a2;
        }
        xr0 = xf4[320 + tid];
        if (tid < 64) xr1 = xf4[320 + 256 + tid];
    }
    __syncthreads();   // Wimg reads done -> region0 becomes Dl

    float d1 = 0.f, d2 = 0.f, mem = 0.f;

    for (int c = 0; c < NCHUNK; ++c) {
        // ---- MFMA phase: D[t 0..31][n 0..511] for this chunk ----
        short8 af[2][2];
#pragma unroll
        for (int m2 = 0; m2 < 2; ++m2)
#pragma unroll
            for (int kf = 0; kf < 2; ++kf)
                af[m2][kf] = *(const short8*)&Aimg[(m2 * 16 + n16) * WSTR
                                                   + kf * 32 + q * 8];
#pragma unroll
        for (int m2 = 0; m2 < 2; ++m2) {
#pragma unroll
            for (int nt = 0; nt < 8; ++nt) {
                f32x4 acc = {0.f, 0.f, 0.f, 0.f};
                acc = __builtin_amdgcn_mfma_f32_16x16x32_bf16(af[m2][0], bfr[nt][0], acc, 0, 0, 0);
                acc = __builtin_amdgcn_mfma_f32_16x16x32_bf16(af[m2][1], bfr[nt][1], acc, 0, 0, 0);
                // C/D: col n = n16, rows t = m2*16 + q*4 + r (4 consecutive)
                const int n  = w * 128 + nt * 16 + n16;
                const int g  = m2 * 4 + q;              // logical granule t>>2
                const int gp = g ^ (n & 7);             // XOR swizzle
                ushort4 dd = { f2bf(acc[0]), f2bf(acc[1]), f2bf(acc[2]), f2bf(acc[3]) };
                *(ushort4*)&Dl[n * 32 + gp * 4] = dd;
            }
        }
        __syncthreads();

        // ---- scan phase: thread = h chain; D1 at col tid, D2 at col tid+256
        {
            const int sw = tid & 7;
#pragma unroll
            for (int g = 0; g < 8; ++g) {
                const int gp = g ^ sw;
                ushort4 u1 = *(const ushort4*)&Dl[tid * 32 + gp * 4];
                ushort4 u2 = *(const ushort4*)&Dl[(tid + 256) * 32 + gp * 4];
                const float i1v[4] = { bf2f(u1.x), bf2f(u1.y), bf2f(u1.z), bf2f(u1.w) };
                const float i2v[4] = { bf2f(u2.x), bf2f(u2.y), bf2f(u2.z), bf2f(u2.w) };
#pragma unroll
                for (int r = 0; r < 4; ++r) {
                    d1  = fmaf(beta1, d1, i1v[r]);
                    d2  = fmaf(beta2, d2, i2v[r]);
                    mem = fmaf(alpha, mem, ia * (d1 + d2));
                    pbuf[(g * 4 + r) * 257 + tid] = mem * wo;
                }
            }
        }

        // ---- A-rewrite (chunk c+1 from regs) + prefetch chunk c+2 ----
        {
            const int m = tid / 10, k0 = (tid % 10) * 4;
            ushort4 a = { f2bf(xr0.x), f2bf(xr0.y), f2bf(xr0.z), f2bf(xr0.w) };
            *(ushort4*)&Aimg[m * WSTR + k0] = a;
            if (tid < 64) {
                const int i2 = 256 + tid, m2 = i2 / 10, k2 = (i2 % 10) * 4;
                ushort4 a2 = { f2bf(xr1.x), f2bf(xr1.y), f2bf(xr1.z), f2bf(xr1.w) };
                *(ushort4*)&Aimg[m2 * WSTR + k2] = a2;
            }
            const int cn = (c + 2 < NCHUNK) ? c + 2 : NCHUNK - 1;
            xr0 = xf4[cn * 320 + tid];
            if (tid < 64) xr1 = xf4[cn * 320 + 256 + tid];
        }
        __syncthreads();

        // ---- reduce phase (R2-verified, conflict-free) ----
        {
            const int t = tid & 31;
            const int j = tid >> 5;
            const float* row = pbuf + t * 257 + j * 32;
            float s0 = 0.f, s1 = 0.f, s2 = 0.f, s3 = 0.f;
#pragma unroll
            for (int m = 0; m < 32; m += 4) {
                s0 += row[m + 0];
                s1 += row[m + 1];
                s2 += row[m + 2];
                s3 += row[m + 3];
            }
            float s = (s0 + s1) + (s2 + s3);
            s += __shfl_down(s, 32, 64);
            if ((tid & 63) < 32) wp[(tid >> 6) * 32 + t] = s;
        }
        __syncthreads();
        if (tid < 32) {
            float r = wp[tid] + wp[32 + tid] + wp[64 + tid] + wp[96 + tid];
            partial[((size_t)hs * NB + b) * NT + c * TT + tid] = r;
        }
        __syncthreads();
    }
}

__global__ __launch_bounds__(256) void sfnn_out_kernel(
    const float* __restrict__ partial, const float* __restrict__ bo,
    float* __restrict__ out)
{
    const int i = blockIdx.x * 256 + threadIdx.x;   // float4 index
    const float bov = bo[0];
    const float4 a = ((const float4*)partial)[i];
    const float4 c = ((const float4*)(partial + (size_t)NB * NT))[i];
    float4 r;
    r.x = 1.f / (1.f + __expf(-(a.x + c.x + bov)));
    r.y = 1.f / (1.f + __expf(-(a.y + c.y + bov)));
    r.z = 1.f / (1.f + __expf(-(a.z + c.z + bov)));
    r.w = 1.f / (1.f + __expf(-(a.w + c.w + bov)));
    ((float4*)out)[i] = r;
}

extern "C" void kernel_launch(void* const* d_in, const int* in_sizes, int n_in,
                              void* d_out, int out_size, void* d_ws, size_t ws_size,
                              hipStream_t stream)
{
    const float* x      = (const float*)d_in[0];
    const float* W1     = (const float*)d_in[1];
    const float* b1     = (const float*)d_in[2];
    const float* W2     = (const float*)d_in[3];
    const float* b2     = (const float*)d_in[4];
    const float* Wo     = (const float*)d_in[5];
    const float* bo     = (const float*)d_in[6];
    const float* tau_m  = (const float*)d_in[7];
    const float* tau_n1 = (const float*)d_in[8];
    const float* tau_n2 = (const float*)d_in[9];

    float* partial = (float*)d_ws;       // 2 * NB * NT floats = 2 MB
    float* out     = (float*)d_out;      // NB * NT floats

    hipLaunchKernelGGL(sfnn_scan_kernel, dim3(NB * 2), dim3(256), 0, stream,
                       x, W1, b1, W2, b2, Wo, tau_m, tau_n1, tau_n2, partial);
    hipLaunchKernelGGL(sfnn_out_kernel, dim3((NB * NT) / (4 * 256)), dim3(256),
                       0, stream, partial, bo, out);
}